// Round 14
// baseline (416.394 us; speedup 1.0000x reference)
//
#include <hip/hip_runtime.h>
#include <hip/hip_bf16.h>

// Sparse conv2d as bf16 implicit GEMM, 256(M) x 224(N) x 64(K-step).
// Software-pipelined: operand reads run one half-tile AHEAD of their MFMA
// cluster, so ds_reads and MFMAs co-execute instead of alternating bursts.
// A: 3-buffer LDS rotation (96 KB); B: per-c-slice 6-row halo block (48 KB)
// resident across 9 taps. One barrier + one covered vmcnt(0) per K-tile.
// x:[32,256,56,56]f32  w_vals:[256,64,3,3]f32  w_idx:[256,64]i32  out:[32,256,56,56]f32
// ws: Wd bf16 [9][256 o][256 c] | Xp bf16 [32][58][58][256]
// Grid 448 tiles of 224 px (3136 = 14*224), bijective XCD swizzle (448=8*56).

typedef __attribute__((ext_vector_type(8))) short bf16x8;
typedef __attribute__((ext_vector_type(4))) float f32x4;

#define WD_BYTES 1179648
#define XP_BYTES 55115776
#define WS_NEED  (WD_BYTES + XP_BYTES)
// LDS: A0 [0,32K) A1 [32K,64K) A2 [64K,96K) Bh [96K,144K)
#define ABUF  32768
#define BHOFF 98304
#define LDS_TOT 147456

// ---------------- fused preprocessing ----------------
__global__ __launch_bounds__(256) void preproc(
    const float* __restrict__ x, const float* __restrict__ wv,
    const int* __restrict__ widx, __hip_bfloat16* __restrict__ wd,
    __hip_bfloat16* __restrict__ xp)
{
    int bid = blockIdx.x;
    int tid = threadIdx.x;
    if (bid >= 1792) {              // ---- scatter_w ----
        int o = bid - 1792;
        int j = tid & 63;
        if (tid < 64) {
#pragma unroll
            for (int k = 0; k < 9; ++k)
                reinterpret_cast<float2*>(wd + (size_t)k * 65536 + o * 256)[j] =
                    float2{0.f, 0.f};
        }
        __syncthreads();
        if (tid < 64) {
            int cin = widx[o * 64 + j];
            const float* src = wv + (size_t)(o * 64 + j) * 9;
#pragma unroll
            for (int k = 0; k < 9; ++k)
                wd[(size_t)k * 65536 + o * 256 + cin] = __float2bfloat16(src[k]);
        }
        return;
    }
    // ---- x_to_nhwc ----
    int b = bid / 56, h = bid - (bid / 56) * 56;
    __shared__ __hip_bfloat16 tile[56][264];
    int c = tid;
    const float* src = x + ((size_t)(b * 256 + c)) * 3136 + h * 56;
    float vals[56];
#pragma unroll
    for (int i = 0; i < 14; ++i) {
        float4 v = *reinterpret_cast<const float4*>(src + i * 4);
        vals[i*4+0] = v.x; vals[i*4+1] = v.y; vals[i*4+2] = v.z; vals[i*4+3] = v.w;
    }
#pragma unroll
    for (int w = 0; w < 56; ++w) tile[w][c] = __float2bfloat16(vals[w]);

    char* rowb = (char*)xp + (((size_t)b * 58 + (h + 1)) * 58) * 512;
    if (tid < 64)        reinterpret_cast<double*>(rowb)[tid] = 0.0;
    else if (tid < 128)  *reinterpret_cast<double*>(rowb + 57 * 512 + (tid - 64) * 8) = 0.0;
    if (h == 0) {
        char* r0 = (char*)xp + (((size_t)b * 58 + 0) * 58) * 512;
        for (int i = tid; i < 58 * 64; i += 256) reinterpret_cast<double*>(r0)[i] = 0.0;
    }
    if (h == 55) {
        char* r57 = (char*)xp + (((size_t)b * 58 + 57) * 58) * 512;
        for (int i = tid; i < 58 * 64; i += 256) reinterpret_cast<double*>(r57)[i] = 0.0;
    }

    __syncthreads();
    char* obase = (char*)xp + (((size_t)b * 58 + (h + 1)) * 58) * 512;
#pragma unroll
    for (int k = 0; k < 7; ++k) {
        int i = tid + k * 256;
        int w = i >> 5, cc = i & 31;
        bf16x8 v = *reinterpret_cast<const bf16x8*>(&tile[w][cc * 8]);
        *reinterpret_cast<bf16x8*>(obase + (size_t)(w + 1) * 512 + cc * 16) = v;
    }
}

// ---------------- GEMM ----------------

__device__ __forceinline__ void gload_lds16(const void* g, void* l) {
    __builtin_amdgcn_global_load_lds(
        (const __attribute__((address_space(1))) void*)g,
        (__attribute__((address_space(3))) void*)l, 16, 0, 0);
}

__device__ __forceinline__ void stage_a4(const char* wdB, char* smem, int dstA,
                                         int wid, int sa_off, int aoff) {
#pragma unroll
    for (int J = 0; J < 4; ++J)
        gload_lds16(wdB + aoff + J * 32768 + sa_off,
                    smem + dstA + (J * 64 + wid * 8) * 128);
}

__device__ __forceinline__ void stage_bh6(const char* xpOcs, char* smem, int wid,
                                          const int (&srcp)[6]) {
#pragma unroll
    for (int j = 0; j < 6; ++j)
        gload_lds16(xpOcs + srcp[j], smem + BHOFF + j * 8192 + wid * 1024);
}

#define BAR() __builtin_amdgcn_s_barrier()
#define VMCNT0() asm volatile("s_waitcnt vmcnt(0)" ::: "memory")

__device__ __forceinline__ void mfma28(bf16x8 (&af)[4], bf16x8 (&bf)[7],
                                       f32x4 (&acc)[4][7]) {
    __builtin_amdgcn_s_setprio(1);
#pragma unroll
    for (int mi = 0; mi < 4; ++mi)
#pragma unroll
        for (int ni = 0; ni < 7; ++ni)
            acc[mi][ni] = __builtin_amdgcn_mfma_f32_16x16x32_bf16(
                af[mi], bf[ni], acc[mi][ni], 0, 0, 0);
    __builtin_amdgcn_s_setprio(0);
}

// One pipelined K-tile, taps TJ = 0..7 (tap 8 is the boundary, inline below).
template<int TJ>
__device__ __forceinline__ void iter_normal(
    const char* wdB, char* smem, int cs,
    int wid, int sa_off, int wrOff, int a_rb, int xq0, int xq1, int g4,
    const int (&rowpl)[7], bf16x8 (&bf0)[7], f32x4 (&acc)[4][7])
{
    constexpr int E   = TJ % 3;
    constexpr int E2  = (TJ + 2) % 3;
    constexpr int SH  = (TJ / 3) * 58 + (TJ % 3);
    constexpr int SHN = ((TJ + 1) / 3) * 58 + ((TJ + 1) % 3);

    // 1: s1(TJ) operands (af1 from A buf E, bf1 from halo @ SH, hi chunk)
    bf16x8 af1[4], bf1[7];
    {
        const int abase = E * ABUF + wrOff + a_rb;
#pragma unroll
        for (int mi = 0; mi < 4; ++mi)
            af1[mi] = *(const bf16x8*)(smem + abase + mi * 2048 + xq1);
#pragma unroll
        for (int n = 0; n < 7; ++n) {
            int roff = rowpl[n] + SH;
            int ba = BHOFF + (roff << 7) + (((g4 ^ (roff & 7)) << 4) ^ 64);
            bf1[n] = *(const bf16x8*)(smem + ba);
        }
    }
    // 2-3: publish A(g+1) (staged mid-previous tile -> covered)
    VMCNT0();
    BAR();
    // 4: af0 just-in-time + MFMA s0(TJ) on bf0 read LAST tile
    bf16x8 af0[4];
    {
        const int abase = E * ABUF + wrOff + a_rb;
#pragma unroll
        for (int mi = 0; mi < 4; ++mi)
            af0[mi] = *(const bf16x8*)(smem + abase + mi * 2048 + xq0);
    }
    mfma28(af0, bf0, acc);
    // 5: stage A(g+2) -> buf E2 (WAR certified by step-3 barrier)
    {
        int aoff2;
        if constexpr (TJ <= 6) aoff2 = (TJ + 2) * 131072 + cs * 128;
        else                   aoff2 = ((cs + 1) & 3) * 128;   // tap0 of next cs
        stage_a4(wdB, smem, E2 * ABUF, wid, sa_off, aoff2);
    }
    // 6: bf0 <- s0(TJ+1) (same halo block; serviced under MFMAs)
#pragma unroll
    for (int n = 0; n < 7; ++n) {
        int roff = rowpl[n] + SHN;
        int ba = BHOFF + (roff << 7) + ((g4 ^ (roff & 7)) << 4);
        bf0[n] = *(const bf16x8*)(smem + ba);
    }
    // 7: MFMA s1(TJ)
    mfma28(af1, bf1, acc);
}

__global__ __launch_bounds__(512, 2) void sparse_conv_mfma224(
    const __hip_bfloat16* __restrict__ wd, const __hip_bfloat16* __restrict__ xp,
    float* __restrict__ out)
{
    extern __shared__ char smem[];
    const char* wdB = (const char*)wd;
    const char* xpB = (const char*)xp;

    const int bid = blockIdx.x;
    const int nt = (bid & 7) * 56 + (bid >> 3);   // bijective XCD swizzle

    const int t = threadIdx.x;
    const int lane = t & 63, wid = t >> 6;   // 8 waves
    const int wr = wid >> 1, wc = wid & 1;   // 4M x 2N wave grid

    const int axor = (((lane & 7) ^ (lane >> 3)) * 16);
    const int sa_off = (wid * 8 + (lane >> 3)) * 512 + axor;

    const int a_rb = (lane & 15) * 128;
    const int xq0 = (((lane >> 4)) ^ (lane & 7)) * 16;
    const int xq1 = ((4 + (lane >> 4)) ^ (lane & 7)) * 16;
    const int wrOff = wr * 8192;

    // B halo geometry
    const int p0 = nt * 224;
    const int bImg = p0 / 3136;
    const int r0 = (p0 - bImg * 3136) / 56;
    const char* xpO = xpB + (size_t)((bImg * 58 + r0) * 58) * 512;

    int srcp[6];
#pragma unroll
    for (int j = 0; j < 6; ++j) {
        int beta = j * 8192 + wid * 1024 + lane * 16;
        int rb = beta >> 7;
        int c  = (beta >> 4) & 7;
        srcp[j] = (rb < 348) ? (rb * 512 + ((c ^ (rb & 7)) << 4)) : 0;
    }

    int rowpl[7];
#pragma unroll
    for (int n = 0; n < 7; ++n) {
        int q = wc * 112 + n * 16 + (lane & 15);
        int qr = q / 56;
        rowpl[n] = qr * 58 + (q - qr * 56);
    }
    const int g4 = lane >> 4;

    f32x4 acc[4][7] = {};
    bf16x8 bf0[7];

    // ---- prologue: Bh(cs0) + A(0)->buf0; publish; preload bf0=s0(0); A(1)->buf1
    stage_bh6(xpO, smem, wid, srcp);
    stage_a4(wdB, smem, 0, wid, sa_off, 0);
    VMCNT0();
    BAR();
#pragma unroll
    for (int n = 0; n < 7; ++n) {
        int roff = rowpl[n];
        int ba = BHOFF + (roff << 7) + ((g4 ^ (roff & 7)) << 4);
        bf0[n] = *(const bf16x8*)(smem + ba);
    }
    stage_a4(wdB, smem, ABUF, wid, sa_off, 131072);   // A(tap1, cs0)

    // ---- main loop: 4 c-slices x 9 taps ----
    for (int cs = 0; cs < 4; ++cs) {
        iter_normal<0>(wdB, smem, cs, wid, sa_off, wrOff, a_rb, xq0, xq1, g4, rowpl, bf0, acc);
        iter_normal<1>(wdB, smem, cs, wid, sa_off, wrOff, a_rb, xq0, xq1, g4, rowpl, bf0, acc);
        iter_normal<2>(wdB, smem, cs, wid, sa_off, wrOff, a_rb, xq0, xq1, g4, rowpl, bf0, acc);
        iter_normal<3>(wdB, smem, cs, wid, sa_off, wrOff, a_rb, xq0, xq1, g4, rowpl, bf0, acc);
        iter_normal<4>(wdB, smem, cs, wid, sa_off, wrOff, a_rb, xq0, xq1, g4, rowpl, bf0, acc);
        iter_normal<5>(wdB, smem, cs, wid, sa_off, wrOff, a_rb, xq0, xq1, g4, rowpl, bf0, acc);
        iter_normal<6>(wdB, smem, cs, wid, sa_off, wrOff, a_rb, xq0, xq1, g4, rowpl, bf0, acc);
        iter_normal<7>(wdB, smem, cs, wid, sa_off, wrOff, a_rb, xq0, xq1, g4, rowpl, bf0, acc);

        // ---- boundary tap 8 ----
        {
            bf16x8 af1[4], bf1[7], af0[4];
            const int abase = 2 * ABUF + wrOff + a_rb;
#pragma unroll
            for (int mi = 0; mi < 4; ++mi)
                af1[mi] = *(const bf16x8*)(smem + abase + mi * 2048 + xq1);
#pragma unroll
            for (int n = 0; n < 7; ++n) {
                int roff = rowpl[n] + 118;
                int ba = BHOFF + (roff << 7) + (((g4 ^ (roff & 7)) << 4) ^ 64);
                bf1[n] = *(const bf16x8*)(smem + ba);
            }
            VMCNT0();   // A(tap0, cs+1) staged at tap7 step 5
            BAR();      // publish it
#pragma unroll
            for (int mi = 0; mi < 4; ++mi)
                af0[mi] = *(const bf16x8*)(smem + abase + mi * 2048 + xq0);
            mfma28(af0, bf0, acc);
            mfma28(af1, bf1, acc);   // forces all own halo reads serviced

            if (cs < 3) {
                BAR();   // all waves' halo/buf2 reads serviced
                stage_bh6(xpO + (cs + 1) * 128, smem, wid, srcp);
                stage_a4(wdB, smem, ABUF, wid, sa_off, 131072 + (cs + 1) * 128);
                VMCNT0();
                BAR();   // publish new halo + A(tap1, cs+1)
#pragma unroll
                for (int n = 0; n < 7; ++n) {
                    int roff = rowpl[n];
                    int ba = BHOFF + (roff << 7) + ((g4 ^ (roff & 7)) << 4);
                    bf0[n] = *(const bf16x8*)(smem + ba);   // s0(tap0, cs+1)
                }
            }
        }
    }

    // ---- epilogue: out[b][o][px] ----
#pragma unroll
    for (int n = 0; n < 7; ++n) {
        int p = nt * 224 + wc * 112 + n * 16;   // wave-uniform; 16 | 3136
        int pb = p / 3136;
        int rem0 = p - pb * 3136;
#pragma unroll
        for (int m = 0; m < 4; ++m) {
            int o = wr * 64 + m * 16 + (lane >> 4) * 4;
            float* dst = out + ((size_t)(pb * 256 + o)) * 3136 + rem0 + (lane & 15);
#pragma unroll
            for (int r = 0; r < 4; ++r) dst[(size_t)r * 3136] = acc[m][n][r];
        }
    }
}

// ---------------- fallback (ws too small) ----------------

__global__ __launch_bounds__(256) void sparse_conv_direct(
    const float* __restrict__ x, const float* __restrict__ wv,
    const int* __restrict__ widx, float* __restrict__ out)
{
    const int bid = blockIdx.x;
    const int b = bid >> 8, o = bid & 255;
    const int tid = threadIdx.x;
    __shared__ float plane[58 * 60];
    const int rt = tid >> 3, ct = tid & 7;
    const int r0 = rt * 2, c0 = ct * 7;
    const bool active = (rt < 28);
    float acc[2][7];
#pragma unroll
    for (int i = 0; i < 2; ++i)
#pragma unroll
        for (int c = 0; c < 7; ++c) acc[i][c] = 0.f;
    const float* xb = x + (size_t)b * 256 * 3136;
    const int* idxp = widx + o * 64;
    const float* wp0 = wv + (size_t)o * 64 * 9;
    for (int j = 0; j < 64; ++j) {
        const int cin = idxp[j];
        const float* src = xb + cin * 3136;
        __syncthreads();
        for (int i = tid; i < 58 * 58; i += 256) {
            const int r = i / 58, c = i - r * 58;
            const int h = r - 1, w = c - 1;
            float v = 0.f;
            if ((unsigned)h < 56u && (unsigned)w < 56u) v = src[h * 56 + w];
            plane[r * 60 + c] = v;
        }
        float wreg[9];
#pragma unroll
        for (int k = 0; k < 9; ++k) wreg[k] = wp0[j * 9 + k];
        __syncthreads();
        if (active) {
            float rows[4][9];
#pragma unroll
            for (int dr = 0; dr < 4; ++dr)
#pragma unroll
                for (int cc = 0; cc < 9; ++cc)
                    rows[dr][cc] = plane[(r0 + dr) * 60 + (c0 + cc)];
#pragma unroll
            for (int i = 0; i < 2; ++i)
#pragma unroll
                for (int cc = 0; cc < 7; ++cc) {
                    float s = acc[i][cc];
#pragma unroll
                    for (int kh = 0; kh < 3; ++kh)
#pragma unroll
                        for (int kw = 0; kw < 3; ++kw)
                            s += rows[i + kh][cc + kw] * wreg[kh * 3 + kw];
                    acc[i][cc] = s;
                }
        }
    }
    if (active) {
        float* op = out + (size_t)bid * 3136;
#pragma unroll
        for (int i = 0; i < 2; ++i)
#pragma unroll
            for (int cc = 0; cc < 7; ++cc)
                op[(r0 + i) * 56 + (c0 + cc)] = acc[i][cc];
    }
}

extern "C" void kernel_launch(void* const* d_in, const int* in_sizes, int n_in,
                              void* d_out, int out_size, void* d_ws, size_t ws_size,
                              hipStream_t stream) {
    const float* x    = (const float*)d_in[0];
    const float* wv   = (const float*)d_in[1];
    const int*   widx = (const int*)d_in[2];
    float* out = (float*)d_out;
    (void)in_sizes; (void)n_in; (void)out_size;

    if (ws_size < (size_t)WS_NEED) {
        sparse_conv_direct<<<dim3(32 * 256), dim3(256), 0, stream>>>(x, wv, widx, out);
        return;
    }

    __hip_bfloat16* wd = (__hip_bfloat16*)d_ws;
    __hip_bfloat16* xp = (__hip_bfloat16*)((char*)d_ws + WD_BYTES);

    preproc<<<dim3(32 * 56 + 256), dim3(256), 0, stream>>>(x, wv, widx, wd, xp);

    (void)hipFuncSetAttribute((const void*)sparse_conv_mfma224,
                              hipFuncAttributeMaxDynamicSharedMemorySize, LDS_TOT);
    sparse_conv_mfma224<<<dim3(448), dim3(512), LDS_TOT, stream>>>(wd, xp, out);
}

// Round 15
// 386.905 us; speedup vs baseline: 1.0762x; 1.0762x over previous
//
#include <hip/hip_runtime.h>
#include <hip/hip_bf16.h>

// Sparse conv2d as bf16 implicit GEMM, 256(M) x 224(N) x 64(K-step).
// c-slice OUTER (4 x 64ch), 3x3 tap INNER. B = 6-row halo block (348 px x
// 128 B, XOR chunk swizzle) resident in LDS across the 9 taps of a c-slice;
// halo reads need NO barrier within a c-slice, so they pipeline under MFMAs.
// A: 3-buffer LDS rotation, counted vmcnt(4) (A published one tap ahead,
// never drained to 0 in-loop). Only bf0 (28 VGPR) is carried across the
// barrier -> non-acc live ~115 VGPR (R14's spill lesson).
// x:[32,256,56,56]f32  w_vals:[256,64,3,3]f32  w_idx:[256,64]i32  out:[32,256,56,56]f32
// ws: Wd bf16 [9][256 o][256 c] | Xp bf16 [32][58][58][256]
// Grid 448 tiles of 224 px (3136 = 14*224), bijective XCD swizzle (448=8*56).

typedef __attribute__((ext_vector_type(8))) short bf16x8;
typedef __attribute__((ext_vector_type(4))) float f32x4;

#define WD_BYTES 1179648
#define XP_BYTES 55115776
#define WS_NEED  (WD_BYTES + XP_BYTES)
// LDS: A0 [0,32K) A1 [32K,64K) A2 [64K,96K) Bh [96K,144K)
#define ABUF  32768
#define BHOFF 98304
#define LDS_TOT 147456

// ---------------- fused preprocessing ----------------
__global__ __launch_bounds__(256) void preproc(
    const float* __restrict__ x, const float* __restrict__ wv,
    const int* __restrict__ widx, __hip_bfloat16* __restrict__ wd,
    __hip_bfloat16* __restrict__ xp)
{
    int bid = blockIdx.x;
    int tid = threadIdx.x;
    if (bid >= 1792) {              // ---- scatter_w ----
        int o = bid - 1792;
        int j = tid & 63;
        if (tid < 64) {
#pragma unroll
            for (int k = 0; k < 9; ++k)
                reinterpret_cast<float2*>(wd + (size_t)k * 65536 + o * 256)[j] =
                    float2{0.f, 0.f};
        }
        __syncthreads();
        if (tid < 64) {
            int cin = widx[o * 64 + j];
            const float* src = wv + (size_t)(o * 64 + j) * 9;
#pragma unroll
            for (int k = 0; k < 9; ++k)
                wd[(size_t)k * 65536 + o * 256 + cin] = __float2bfloat16(src[k]);
        }
        return;
    }
    // ---- x_to_nhwc ----
    int b = bid / 56, h = bid - (bid / 56) * 56;
    __shared__ __hip_bfloat16 tile[56][264];
    int c = tid;
    const float* src = x + ((size_t)(b * 256 + c)) * 3136 + h * 56;
    float vals[56];
#pragma unroll
    for (int i = 0; i < 14; ++i) {
        float4 v = *reinterpret_cast<const float4*>(src + i * 4);
        vals[i*4+0] = v.x; vals[i*4+1] = v.y; vals[i*4+2] = v.z; vals[i*4+3] = v.w;
    }
#pragma unroll
    for (int w = 0; w < 56; ++w) tile[w][c] = __float2bfloat16(vals[w]);

    char* rowb = (char*)xp + (((size_t)b * 58 + (h + 1)) * 58) * 512;
    if (tid < 64)        reinterpret_cast<double*>(rowb)[tid] = 0.0;
    else if (tid < 128)  *reinterpret_cast<double*>(rowb + 57 * 512 + (tid - 64) * 8) = 0.0;
    if (h == 0) {
        char* r0 = (char*)xp + (((size_t)b * 58 + 0) * 58) * 512;
        for (int i = tid; i < 58 * 64; i += 256) reinterpret_cast<double*>(r0)[i] = 0.0;
    }
    if (h == 55) {
        char* r57 = (char*)xp + (((size_t)b * 58 + 57) * 58) * 512;
        for (int i = tid; i < 58 * 64; i += 256) reinterpret_cast<double*>(r57)[i] = 0.0;
    }

    __syncthreads();
    char* obase = (char*)xp + (((size_t)b * 58 + (h + 1)) * 58) * 512;
#pragma unroll
    for (int k = 0; k < 7; ++k) {
        int i = tid + k * 256;
        int w = i >> 5, cc = i & 31;
        bf16x8 v = *reinterpret_cast<const bf16x8*>(&tile[w][cc * 8]);
        *reinterpret_cast<bf16x8*>(obase + (size_t)(w + 1) * 512 + cc * 16) = v;
    }
}

// ---------------- GEMM ----------------

__device__ __forceinline__ void gload_lds16(const void* g, void* l) {
    __builtin_amdgcn_global_load_lds(
        (const __attribute__((address_space(1))) void*)g,
        (__attribute__((address_space(3))) void*)l, 16, 0, 0);
}

__device__ __forceinline__ void stage_a4(const char* wdB, char* smem, int dstA,
                                         int wid, int sa_off, int aoff) {
#pragma unroll
    for (int J = 0; J < 4; ++J)
        gload_lds16(wdB + aoff + J * 32768 + sa_off,
                    smem + dstA + (J * 64 + wid * 8) * 128);
}

// B halo: 348 px x 128 B, chunk-XOR swizzle; srcp computed inline (saves VGPRs).
__device__ __forceinline__ void stage_bh6(const char* xpOcs, char* smem,
                                          int wid, int lane) {
#pragma unroll
    for (int j = 0; j < 6; ++j) {
        int beta = j * 8192 + wid * 1024 + lane * 16;
        int rb = beta >> 7;
        int c  = (beta >> 4) & 7;
        int src = (rb < 348) ? (rb * 512 + ((c ^ (rb & 7)) << 4)) : 0;
        gload_lds16(xpOcs + src, smem + BHOFF + j * 8192 + wid * 1024);
    }
}

#define BAR() __builtin_amdgcn_s_barrier()
#define VMCNT0() asm volatile("s_waitcnt vmcnt(0)" ::: "memory")
#define VMCNT4() asm volatile("s_waitcnt vmcnt(4)" ::: "memory")

__device__ __forceinline__ void mfma28(bf16x8 (&af)[4], bf16x8 (&bf)[7],
                                       f32x4 (&acc)[4][7]) {
    __builtin_amdgcn_s_setprio(1);
#pragma unroll
    for (int mi = 0; mi < 4; ++mi)
#pragma unroll
        for (int ni = 0; ni < 7; ++ni)
            acc[mi][ni] = __builtin_amdgcn_mfma_f32_16x16x32_bf16(
                af[mi], bf[ni], acc[mi][ni], 0, 0, 0);
    __builtin_amdgcn_s_setprio(0);
}

// Tap T of c-slice cs. Invariant entering: A(g) published in buf T%3;
// bf0 = halo h0-operands for tap T. Exiting (T<=7): A(g+1) published,
// bf0 = tap T+1 operands. g%3 == T%3 (9 = 0 mod 3) -> bufs compile-time.
template<int T>
__device__ __forceinline__ void tap_iter(
    const char* wdB, char* smem, int cs,
    int wid, int sa_off, int wrOff, int a_rb, int xq0, int xq1, int g4,
    const int (&rowpl)[7], bf16x8 (&bf0)[7], f32x4 (&acc)[4][7])
{
    constexpr int BUF  = T % 3;
    constexpr int BUF2 = (T + 2) % 3;
    constexpr int SH   = (T / 3) * 58 + (T % 3);
    constexpr int TAP2 = (T + 2) % 9;
    constexpr int CSI  = (T + 2) / 9;

    const int abase = BUF * ABUF + wrOff + a_rb;

    // af0 just-in-time (only barrier-pinned reads of the tap)
    bf16x8 af0[4];
#pragma unroll
    for (int mi = 0; mi < 4; ++mi)
        af0[mi] = *(const bf16x8*)(smem + abase + mi * 2048 + xq0);

    // stage A(g+2) -> buf (T+2)%3 (WAR: its readers passed last tap's barrier)
    stage_a4(wdB, smem, BUF2 * ABUF, wid, sa_off,
             TAP2 * 131072 + ((cs + CSI) & 3) * 128);

    // MFMA h0 (bf0 carried in)
    mfma28(af0, bf0, acc);

    // h1 operands (serviced under h0's MFMA window)
    bf16x8 af1[4], bf1[7];
#pragma unroll
    for (int mi = 0; mi < 4; ++mi)
        af1[mi] = *(const bf16x8*)(smem + abase + mi * 2048 + xq1);
#pragma unroll
    for (int n = 0; n < 7; ++n) {
        int roff = rowpl[n] + SH;
        int ba = BHOFF + (roff << 7) + (((g4 ^ (roff & 7)) << 4) ^ 64);
        bf1[n] = *(const bf16x8*)(smem + ba);
    }

    // MFMA h1
    mfma28(af1, bf1, acc);

    if constexpr (T <= 7) {
        // bf0 <- tap T+1 (same halo, no barrier needed; serviced under h1)
        constexpr int SHN = ((T + 1) / 3) * 58 + ((T + 1) % 3);
#pragma unroll
        for (int n = 0; n < 7; ++n) {
            int roff = rowpl[n] + SHN;
            int ba = BHOFF + (roff << 7) + ((g4 ^ (roff & 7)) << 4);
            bf0[n] = *(const bf16x8*)(smem + ba);
        }
        VMCNT4();   // outstanding: A(g+2)[4] -> A(g+1) drained (counted, not 0)
        BAR();      // publish A(g+1); certify this tap's reads done (WAR)
    }
}

__global__ __launch_bounds__(512, 2) void sparse_conv_mfma224(
    const __hip_bfloat16* __restrict__ wd, const __hip_bfloat16* __restrict__ xp,
    float* __restrict__ out)
{
    extern __shared__ char smem[];
    const char* wdB = (const char*)wd;
    const char* xpB = (const char*)xp;

    const int bid = blockIdx.x;
    const int nt = (bid & 7) * 56 + (bid >> 3);   // bijective XCD swizzle

    const int t = threadIdx.x;
    const int lane = t & 63, wid = t >> 6;   // 8 waves
    const int wr = wid >> 1, wc = wid & 1;   // 4M x 2N wave grid

    const int axor = (((lane & 7) ^ (lane >> 3)) * 16);
    const int sa_off = (wid * 8 + (lane >> 3)) * 512 + axor;

    const int a_rb = (lane & 15) * 128;
    const int xq0 = (((lane >> 4)) ^ (lane & 7)) * 16;
    const int xq1 = ((4 + (lane >> 4)) ^ (lane & 7)) * 16;
    const int wrOff = wr * 8192;

    // B halo geometry
    const int p0 = nt * 224;
    const int bImg = p0 / 3136;
    const int r0 = (p0 - bImg * 3136) / 56;
    const char* xpO = xpB + (size_t)((bImg * 58 + r0) * 58) * 512;

    int rowpl[7];
#pragma unroll
    for (int n = 0; n < 7; ++n) {
        int q = wc * 112 + n * 16 + (lane & 15);
        int qr = q / 56;
        rowpl[n] = qr * 58 + (q - qr * 56);
    }
    const int g4 = lane >> 4;

    f32x4 acc[4][7] = {};
    bf16x8 bf0[7];

    // ---- prologue: halo(cs0) + A(0) -> buf0; publish; bf0 <- tap0; A(1) -> buf1
    stage_bh6(xpO, smem, wid, lane);
    stage_a4(wdB, smem, 0, wid, sa_off, 0);
    VMCNT0();
    BAR();
#pragma unroll
    for (int n = 0; n < 7; ++n) {
        int roff = rowpl[n];
        int ba = BHOFF + (roff << 7) + ((g4 ^ (roff & 7)) << 4);
        bf0[n] = *(const bf16x8*)(smem + ba);
    }
    stage_a4(wdB, smem, ABUF, wid, sa_off, 131072);   // A(tap1, cs0)

    // ---- main loop: 4 c-slices x 9 taps ----
    for (int cs = 0; cs < 4; ++cs) {
        tap_iter<0>(wdB, smem, cs, wid, sa_off, wrOff, a_rb, xq0, xq1, g4, rowpl, bf0, acc);
        tap_iter<1>(wdB, smem, cs, wid, sa_off, wrOff, a_rb, xq0, xq1, g4, rowpl, bf0, acc);
        tap_iter<2>(wdB, smem, cs, wid, sa_off, wrOff, a_rb, xq0, xq1, g4, rowpl, bf0, acc);
        tap_iter<3>(wdB, smem, cs, wid, sa_off, wrOff, a_rb, xq0, xq1, g4, rowpl, bf0, acc);
        tap_iter<4>(wdB, smem, cs, wid, sa_off, wrOff, a_rb, xq0, xq1, g4, rowpl, bf0, acc);
        tap_iter<5>(wdB, smem, cs, wid, sa_off, wrOff, a_rb, xq0, xq1, g4, rowpl, bf0, acc);
        tap_iter<6>(wdB, smem, cs, wid, sa_off, wrOff, a_rb, xq0, xq1, g4, rowpl, bf0, acc);
        tap_iter<7>(wdB, smem, cs, wid, sa_off, wrOff, a_rb, xq0, xq1, g4, rowpl, bf0, acc);
        tap_iter<8>(wdB, smem, cs, wid, sa_off, wrOff, a_rb, xq0, xq1, g4, rowpl, bf0, acc);

        // ---- c-slice boundary ----
        if (cs < 3) {
            VMCNT4();   // outstanding: A(tap1,cs+1)[4] -> A(tap0,cs+1) drained
            BAR();      // publish A(tap0,cs+1); old-halo readers certified done
            stage_bh6(xpO + (cs + 1) * 128, smem, wid, lane);
            VMCNT0();   // drain halo (+A(tap1,cs+1) early) - 3x/block, cheap
            BAR();      // publish new halo + A(tap1,cs+1)
#pragma unroll
            for (int n = 0; n < 7; ++n) {
                int roff = rowpl[n];
                int ba = BHOFF + (roff << 7) + ((g4 ^ (roff & 7)) << 4);
                bf0[n] = *(const bf16x8*)(smem + ba);   // tap0 of cs+1
            }
        }
    }

    // ---- epilogue: out[b][o][px] ----
#pragma unroll
    for (int n = 0; n < 7; ++n) {
        int p = nt * 224 + wc * 112 + n * 16;   // wave-uniform; 16 | 3136
        int pb = p / 3136;
        int rem0 = p - pb * 3136;
#pragma unroll
        for (int m = 0; m < 4; ++m) {
            int o = wr * 64 + m * 16 + (lane >> 4) * 4;
            float* dst = out + ((size_t)(pb * 256 + o)) * 3136 + rem0 + (lane & 15);
#pragma unroll
            for (int r = 0; r < 4; ++r) dst[(size_t)r * 3136] = acc[m][n][r];
        }
    }
}

// ---------------- fallback (ws too small) ----------------

__global__ __launch_bounds__(256) void sparse_conv_direct(
    const float* __restrict__ x, const float* __restrict__ wv,
    const int* __restrict__ widx, float* __restrict__ out)
{
    const int bid = blockIdx.x;
    const int b = bid >> 8, o = bid & 255;
    const int tid = threadIdx.x;
    __shared__ float plane[58 * 60];
    const int rt = tid >> 3, ct = tid & 7;
    const int r0 = rt * 2, c0 = ct * 7;
    const bool active = (rt < 28);
    float acc[2][7];
#pragma unroll
    for (int i = 0; i < 2; ++i)
#pragma unroll
        for (int c = 0; c < 7; ++c) acc[i][c] = 0.f;
    const float* xb = x + (size_t)b * 256 * 3136;
    const int* idxp = widx + o * 64;
    const float* wp0 = wv + (size_t)o * 64 * 9;
    for (int j = 0; j < 64; ++j) {
        const int cin = idxp[j];
        const float* src = xb + cin * 3136;
        __syncthreads();
        for (int i = tid; i < 58 * 58; i += 256) {
            const int r = i / 58, c = i - r * 58;
            const int h = r - 1, w = c - 1;
            float v = 0.f;
            if ((unsigned)h < 56u && (unsigned)w < 56u) v = src[h * 56 + w];
            plane[r * 60 + c] = v;
        }
        float wreg[9];
#pragma unroll
        for (int k = 0; k < 9; ++k) wreg[k] = wp0[j * 9 + k];
        __syncthreads();
        if (active) {
            float rows[4][9];
#pragma unroll
            for (int dr = 0; dr < 4; ++dr)
#pragma unroll
                for (int cc = 0; cc < 9; ++cc)
                    rows[dr][cc] = plane[(r0 + dr) * 60 + (c0 + cc)];
#pragma unroll
            for (int i = 0; i < 2; ++i)
#pragma unroll
                for (int cc = 0; cc < 7; ++cc) {
                    float s = acc[i][cc];
#pragma unroll
                    for (int kh = 0; kh < 3; ++kh)
#pragma unroll
                        for (int kw = 0; kw < 3; ++kw)
                            s += rows[i + kh][cc + kw] * wreg[kh * 3 + kw];
                    acc[i][cc] = s;
                }
        }
    }
    if (active) {
        float* op = out + (size_t)bid * 3136;
#pragma unroll
        for (int i = 0; i < 2; ++i)
#pragma unroll
            for (int cc = 0; cc < 7; ++cc)
                op[(r0 + i) * 56 + (c0 + cc)] = acc[i][cc];
    }
}

extern "C" void kernel_launch(void* const* d_in, const int* in_sizes, int n_in,
                              void* d_out, int out_size, void* d_ws, size_t ws_size,
                              hipStream_t stream) {
    const float* x    = (const float*)d_in[0];
    const float* wv   = (const float*)d_in[1];
    const int*   widx = (const int*)d_in[2];
    float* out = (float*)d_out;
    (void)in_sizes; (void)n_in; (void)out_size;

    if (ws_size < (size_t)WS_NEED) {
        sparse_conv_direct<<<dim3(32 * 256), dim3(256), 0, stream>>>(x, wv, widx, out);
        return;
    }

    __hip_bfloat16* wd = (__hip_bfloat16*)d_ws;
    __hip_bfloat16* xp = (__hip_bfloat16*)((char*)d_ws + WD_BYTES);

    preproc<<<dim3(32 * 56 + 256), dim3(256), 0, stream>>>(x, wv, widx, wd, xp);

    (void)hipFuncSetAttribute((const void*)sparse_conv_mfma224,
                              hipFuncAttributeMaxDynamicSharedMemorySize, LDS_TOT);
    sparse_conv_mfma224<<<dim3(448), dim3(512), LDS_TOT, stream>>>(wd, xp, out);
}

// Round 16
// 125.045 us; speedup vs baseline: 3.3300x; 3.0941x over previous
//
#include <hip/hip_runtime.h>
#include <hip/hip_bf16.h>

// Sparse conv2d as bf16 implicit GEMM, 128(M) x 224(N) x 64(K-step),
// TWO BLOCKS PER CU (anti-phase): independent barriers let one block's
// ds_read burst overlap the other's MFMA burst (m114), costing 0 registers.
// Per block: 4 waves (2M x 2N, wave tile 64x112), A dbuf 32K + B halo 44K
// (6-row block, stride 128, XOR chunk swizzle) = 76 KB LDS -> 2 blocks/CU.
// Schedule per tap = R13's proven simple form (VGPR ~120, no spill).
// x:[32,256,56,56]f32  w_vals:[256,64,3,3]f32  w_idx:[256,64]i32  out:[32,256,56,56]f32
// ws: Wd bf16 [9][256 o][256 c] | Xp bf16 [32][58][58][256]
// Grid 896 = 448 nt x 2 mt (8*112 XCD swizzle; mt pair shares halo on one XCD).

typedef __attribute__((ext_vector_type(8))) short bf16x8;
typedef __attribute__((ext_vector_type(4))) float f32x4;

#define WD_BYTES 1179648
#define XP_BYTES 55115776
#define WS_NEED  (WD_BYTES + XP_BYTES)
// LDS per block: A0 [0,16K) A1 [16K,32K) Bh [32K, 32K+45056)
#define ABUF  16384
#define BHOFF 32768
#define LDS_TOT 77824

// ---------------- fused preprocessing ----------------
__global__ __launch_bounds__(256) void preproc(
    const float* __restrict__ x, const float* __restrict__ wv,
    const int* __restrict__ widx, __hip_bfloat16* __restrict__ wd,
    __hip_bfloat16* __restrict__ xp)
{
    int bid = blockIdx.x;
    int tid = threadIdx.x;
    if (bid >= 1792) {              // ---- scatter_w ----
        int o = bid - 1792;
        int j = tid & 63;
        if (tid < 64) {
#pragma unroll
            for (int k = 0; k < 9; ++k)
                reinterpret_cast<float2*>(wd + (size_t)k * 65536 + o * 256)[j] =
                    float2{0.f, 0.f};
        }
        __syncthreads();
        if (tid < 64) {
            int cin = widx[o * 64 + j];
            const float* src = wv + (size_t)(o * 64 + j) * 9;
#pragma unroll
            for (int k = 0; k < 9; ++k)
                wd[(size_t)k * 65536 + o * 256 + cin] = __float2bfloat16(src[k]);
        }
        return;
    }
    // ---- x_to_nhwc ----
    int b = bid / 56, h = bid - (bid / 56) * 56;
    __shared__ __hip_bfloat16 tile[56][264];
    int c = tid;
    const float* src = x + ((size_t)(b * 256 + c)) * 3136 + h * 56;
    float vals[56];
#pragma unroll
    for (int i = 0; i < 14; ++i) {
        float4 v = *reinterpret_cast<const float4*>(src + i * 4);
        vals[i*4+0] = v.x; vals[i*4+1] = v.y; vals[i*4+2] = v.z; vals[i*4+3] = v.w;
    }
#pragma unroll
    for (int w = 0; w < 56; ++w) tile[w][c] = __float2bfloat16(vals[w]);

    char* rowb = (char*)xp + (((size_t)b * 58 + (h + 1)) * 58) * 512;
    if (tid < 64)        reinterpret_cast<double*>(rowb)[tid] = 0.0;
    else if (tid < 128)  *reinterpret_cast<double*>(rowb + 57 * 512 + (tid - 64) * 8) = 0.0;
    if (h == 0) {
        char* r0 = (char*)xp + (((size_t)b * 58 + 0) * 58) * 512;
        for (int i = tid; i < 58 * 64; i += 256) reinterpret_cast<double*>(r0)[i] = 0.0;
    }
    if (h == 55) {
        char* r57 = (char*)xp + (((size_t)b * 58 + 57) * 58) * 512;
        for (int i = tid; i < 58 * 64; i += 256) reinterpret_cast<double*>(r57)[i] = 0.0;
    }

    __syncthreads();
    char* obase = (char*)xp + (((size_t)b * 58 + (h + 1)) * 58) * 512;
#pragma unroll
    for (int k = 0; k < 7; ++k) {
        int i = tid + k * 256;
        int w = i >> 5, cc = i & 31;
        bf16x8 v = *reinterpret_cast<const bf16x8*>(&tile[w][cc * 8]);
        *reinterpret_cast<bf16x8*>(obase + (size_t)(w + 1) * 512 + cc * 16) = v;
    }
}

// ---------------- GEMM ----------------

__device__ __forceinline__ void gload_lds16(const void* g, void* l) {
    __builtin_amdgcn_global_load_lds(
        (const __attribute__((address_space(1))) void*)g,
        (__attribute__((address_space(3))) void*)l, 16, 0, 0);
}

// A-tile [128 rows][128 B] (block's mt half). 4 instrs x 4 KB (32 rows each);
// 256 threads: row = J*32 + wid*8 + lane>>3.
__device__ __forceinline__ void stage_a4(const char* wdB, char* smem, int dstA,
                                         int wid, int sa_off, int aoff) {
#pragma unroll
    for (int J = 0; J < 4; ++J)
        gload_lds16(wdB + aoff + J * 16384 + sa_off,
                    smem + dstA + (J * 32 + wid * 8) * 128);
}

// B halo: 348 px x 128 B, stride 128, chunk-XOR swizzle. 11 instrs x 4 KB
// (rows 348..351 padding: source clamped, never read).
__device__ __forceinline__ void stage_bh11(const char* xpOcs, char* smem,
                                           int wid, int lane) {
#pragma unroll
    for (int j = 0; j < 11; ++j) {
        int beta = j * 4096 + wid * 1024 + lane * 16;
        int rb = beta >> 7;
        int c  = (beta >> 4) & 7;
        int src = (rb < 348) ? (rb * 512 + ((c ^ (rb & 7)) << 4)) : 0;
        gload_lds16(xpOcs + src, smem + BHOFF + j * 4096 + wid * 1024);
    }
}

#define BAR() __builtin_amdgcn_s_barrier()
#define VMCNT0() asm volatile("s_waitcnt vmcnt(0)" ::: "memory")

__global__ __launch_bounds__(256, 2) void sparse_conv_mfma2b(
    const __hip_bfloat16* __restrict__ wd, const __hip_bfloat16* __restrict__ xp,
    float* __restrict__ out)
{
    extern __shared__ char smem[];
    const char* wdB = (const char*)wd;
    const char* xpB = (const char*)xp;

    // XCD swizzle: 896 = 8 * 112; consecutive swz share nt (mt pair) per XCD
    const int bid = blockIdx.x;
    const int swz = (bid & 7) * 112 + (bid >> 3);
    const int mt = swz & 1;
    const int nt = swz >> 1;          // 0..447

    const int t = threadIdx.x;
    const int lane = t & 63, wid = t >> 6;   // 4 waves
    const int wr = wid >> 1, wc = wid & 1;   // 2M x 2N wave grid

    // A staging constants (pre-swizzled global source, linear LDS dest)
    const int axor = (((lane & 7) ^ (lane >> 3)) * 16);
    const int sa_off = (wid * 8 + (lane >> 3)) * 512 + axor;
    const int mtOff = mt * 65536;     // 128 rows x 512 B

    // A fragment-read constants (XOR matches staging pre-swizzle)
    const int a_rb = (lane & 15) * 128;
    const int xq0 = (((lane >> 4)) ^ (lane & 7)) * 16;
    const int xq1 = ((4 + (lane >> 4)) ^ (lane & 7)) * 16;
    const int wrOff = wr * 8192;      // 64 rows x 128 B

    // B halo geometry (tile = image rows r0..r0+3 of batch bImg)
    const int p0 = nt * 224;
    const int bImg = p0 / 3136;
    const int r0 = (p0 - bImg * 3136) / 56;
    const char* xpO = xpB + (size_t)((bImg * 58 + r0) * 58) * 512;

    int rowpl[7];
#pragma unroll
    for (int n = 0; n < 7; ++n) {
        int q = wc * 112 + n * 16 + (lane & 15);
        int qr = q / 56;
        rowpl[n] = qr * 58 + (q - qr * 56);
    }
    const int g4 = lane >> 4;

    f32x4 acc[4][7] = {};

    // ---- prologue: halo(cs0) + A(tap0) -> buf0 ----
    stage_bh11(xpO, smem, wid, lane);
    stage_a4(wdB, smem, 0, wid, sa_off, mtOff);
    VMCNT0();
    BAR();

    // ---- main loop: 36 tiles = 4 cs x 9 taps (R13 schedule) ----
    int k9 = 0, cs = 0, shift = 0;
    for (int g = 0; g < 36; ++g) {
        int k9n = k9 + 1, csn = cs;
        if (k9n == 9) { k9n = 0; csn = cs + 1; if (csn == 4) csn = 0; }
        stage_a4(wdB, smem, ((g + 1) & 1) * ABUF, wid, sa_off,
                 k9n * 131072 + mtOff + csn * 128);

        const int abase = (g & 1) * ABUF + wrOff + a_rb;
        bf16x8 af0[4], af1[4], bf0[7], bf1[7];
#pragma unroll
        for (int mi = 0; mi < 4; ++mi) {
            af0[mi] = *(const bf16x8*)(smem + abase + mi * 2048 + xq0);
            af1[mi] = *(const bf16x8*)(smem + abase + mi * 2048 + xq1);
        }
#pragma unroll
        for (int n = 0; n < 7; ++n) {
            int roff = rowpl[n] + shift;
            int ba = BHOFF + (roff << 7) + ((g4 ^ (roff & 7)) << 4);
            bf0[n] = *(const bf16x8*)(smem + ba);
            bf1[n] = *(const bf16x8*)(smem + (ba ^ 64));   // chunk g4+4
        }

        __builtin_amdgcn_s_setprio(1);
#pragma unroll
        for (int mi = 0; mi < 4; ++mi)
#pragma unroll
            for (int ni = 0; ni < 7; ++ni)
                acc[mi][ni] = __builtin_amdgcn_mfma_f32_16x16x32_bf16(
                    af0[mi], bf0[ni], acc[mi][ni], 0, 0, 0);
#pragma unroll
        for (int mi = 0; mi < 4; ++mi)
#pragma unroll
            for (int ni = 0; ni < 7; ++ni)
                acc[mi][ni] = __builtin_amdgcn_mfma_f32_16x16x32_bf16(
                    af1[mi], bf1[ni], acc[mi][ni], 0, 0, 0);
        __builtin_amdgcn_s_setprio(0);

        VMCNT0();   // 4 A-ops (L2-hot), covered by the 56-MFMA window
        BAR();      // A buf handoff; halo reads of this tile complete

        if (k9n == 0) {
            if (csn != 0) {
                stage_bh11(xpO + csn * 128, smem, wid, lane);
                VMCNT0();
                BAR();
            }
            shift = 0;
        } else {
            shift += ((k9n % 3) == 0) ? 56 : 1;   // kh*58+kw walk
        }
        k9 = k9n; cs = csn;
    }

    // ---- epilogue: out[b][o][px] ----
#pragma unroll
    for (int n = 0; n < 7; ++n) {
        int p = nt * 224 + wc * 112 + n * 16;   // wave-uniform; 16 | 3136
        int pb = p / 3136;
        int rem0 = p - pb * 3136;
#pragma unroll
        for (int m = 0; m < 4; ++m) {
            int o = mt * 128 + wr * 64 + m * 16 + (lane >> 4) * 4;
            float* dst = out + ((size_t)(pb * 256 + o)) * 3136 + rem0 + (lane & 15);
#pragma unroll
            for (int r = 0; r < 4; ++r) dst[(size_t)r * 3136] = acc[m][n][r];
        }
    }
}

// ---------------- fallback (ws too small) ----------------

__global__ __launch_bounds__(256) void sparse_conv_direct(
    const float* __restrict__ x, const float* __restrict__ wv,
    const int* __restrict__ widx, float* __restrict__ out)
{
    const int bid = blockIdx.x;
    const int b = bid >> 8, o = bid & 255;
    const int tid = threadIdx.x;
    __shared__ float plane[58 * 60];
    const int rt = tid >> 3, ct = tid & 7;
    const int r0 = rt * 2, c0 = ct * 7;
    const bool active = (rt < 28);
    float acc[2][7];
#pragma unroll
    for (int i = 0; i < 2; ++i)
#pragma unroll
        for (int c = 0; c < 7; ++c) acc[i][c] = 0.f;
    const float* xb = x + (size_t)b * 256 * 3136;
    const int* idxp = widx + o * 64;
    const float* wp0 = wv + (size_t)o * 64 * 9;
    for (int j = 0; j < 64; ++j) {
        const int cin = idxp[j];
        const float* src = xb + cin * 3136;
        __syncthreads();
        for (int i = tid; i < 58 * 58; i += 256) {
            const int r = i / 58, c = i - r * 58;
            const int h = r - 1, w = c - 1;
            float v = 0.f;
            if ((unsigned)h < 56u && (unsigned)w < 56u) v = src[h * 56 + w];
            plane[r * 60 + c] = v;
        }
        float wreg[9];
#pragma unroll
        for (int k = 0; k < 9; ++k) wreg[k] = wp0[j * 9 + k];
        __syncthreads();
        if (active) {
            float rows[4][9];
#pragma unroll
            for (int dr = 0; dr < 4; ++dr)
#pragma unroll
                for (int cc = 0; cc < 9; ++cc)
                    rows[dr][cc] = plane[(r0 + dr) * 60 + (c0 + cc)];
#pragma unroll
            for (int i = 0; i < 2; ++i)
#pragma unroll
                for (int cc = 0; cc < 7; ++cc) {
                    float s = acc[i][cc];
#pragma unroll
                    for (int kh = 0; kh < 3; ++kh)
#pragma unroll
                        for (int kw = 0; kw < 3; ++kw)
                            s += rows[i + kh][cc + kw] * wreg[kh * 3 + kw];
                    acc[i][cc] = s;
                }
        }
    }
    if (active) {
        float* op = out + (size_t)bid * 3136;
#pragma unroll
        for (int i = 0; i < 2; ++i)
#pragma unroll
            for (int cc = 0; cc < 7; ++cc)
                op[(r0 + i) * 56 + (c0 + cc)] = acc[i][cc];
    }
}

extern "C" void kernel_launch(void* const* d_in, const int* in_sizes, int n_in,
                              void* d_out, int out_size, void* d_ws, size_t ws_size,
                              hipStream_t stream) {
    const float* x    = (const float*)d_in[0];
    const float* wv   = (const float*)d_in[1];
    const int*   widx = (const int*)d_in[2];
    float* out = (float*)d_out;
    (void)in_sizes; (void)n_in; (void)out_size;

    if (ws_size < (size_t)WS_NEED) {
        sparse_conv_direct<<<dim3(32 * 256), dim3(256), 0, stream>>>(x, wv, widx, out);
        return;
    }

    __hip_bfloat16* wd = (__hip_bfloat16*)d_ws;
    __hip_bfloat16* xp = (__hip_bfloat16*)((char*)d_ws + WD_BYTES);

    preproc<<<dim3(32 * 56 + 256), dim3(256), 0, stream>>>(x, wv, widx, wd, xp);

    (void)hipFuncSetAttribute((const void*)sparse_conv_mfma2b,
                              hipFuncAttributeMaxDynamicSharedMemorySize, LDS_TOT);
    sparse_conv_mfma2b<<<dim3(896), dim3(256), LDS_TOT, stream>>>(wd, xp, out);
}